// Round 1
// 287.161 us; speedup vs baseline: 1.0017x; 1.0017x over previous
//
#include <hip/hip_runtime.h>
#include <math.h>

#define NNB   576          // sequence length N
#define BNR   4608         // B*N rows
#define KSEL  51           // top-k along D

typedef unsigned short u16;
typedef __attribute__((ext_vector_type(8))) short bf16x8;
typedef __attribute__((ext_vector_type(4))) float f32x4;

// round-to-nearest (ties up) f32 -> bf16; inputs are finite
__device__ __forceinline__ u16 f2bf(float f) {
    unsigned u = __float_as_uint(f);
    return (u16)((u + 0x8000u) >> 16);
}
__device__ __forceinline__ unsigned pack2(float a, float b) {
    unsigned ua = __float_as_uint(a), ub = __float_as_uint(b);
    return ((ua + 0x8000u) >> 16) | ((ub + 0x8000u) & 0xffff0000u);
}
// async global->LDS DMA, 16B per lane; LDS dst = base + lane*16 (wave-uniform base)
__device__ __forceinline__ void load_lds16(const void* gp, void* lp) {
    __builtin_amdgcn_global_load_lds((const __attribute__((address_space(1))) void*)gp,
                                     (__attribute__((address_space(3))) void*)lp, 16, 0, 0);
}
// full-wave64 sum via DPP (row_shr 1/2/4/8, bcast15, bcast31), result uniform
__device__ __forceinline__ int dpp_red_add_i(int v) {
    v += __builtin_amdgcn_update_dpp(0, v, 0x111, 0xf, 0xf, true);
    v += __builtin_amdgcn_update_dpp(0, v, 0x112, 0xf, 0xf, true);
    v += __builtin_amdgcn_update_dpp(0, v, 0x114, 0xf, 0xf, true);
    v += __builtin_amdgcn_update_dpp(0, v, 0x118, 0xf, 0xf, true);
    v += __builtin_amdgcn_update_dpp(0, v, 0x142, 0xa, 0xf, true);
    v += __builtin_amdgcn_update_dpp(0, v, 0x143, 0xc, 0xf, true);
    return __builtin_amdgcn_readlane(v, 63);
}
__device__ __forceinline__ float dpp_red_add_f(float x) {
    x += __int_as_float(__builtin_amdgcn_update_dpp(0, __float_as_int(x), 0x111, 0xf, 0xf, true));
    x += __int_as_float(__builtin_amdgcn_update_dpp(0, __float_as_int(x), 0x112, 0xf, 0xf, true));
    x += __int_as_float(__builtin_amdgcn_update_dpp(0, __float_as_int(x), 0x114, 0xf, 0xf, true));
    x += __int_as_float(__builtin_amdgcn_update_dpp(0, __float_as_int(x), 0x118, 0xf, 0xf, true));
    x += __int_as_float(__builtin_amdgcn_update_dpp(0, __float_as_int(x), 0x142, 0xa, 0xf, true));
    x += __int_as_float(__builtin_amdgcn_update_dpp(0, __float_as_int(x), 0x143, 0xc, 0xf, true));
    return __int_as_float(__builtin_amdgcn_readlane(__float_as_int(x), 63));
}

// ---------------------------------------------------------------------------
// Cast F, in_proj_w, out_proj_w, w1 to bf16 (segment boundaries block-aligned)
// ---------------------------------------------------------------------------
__global__ __launch_bounds__(256)
void cast_bf16(const float* __restrict__ F, const float* __restrict__ ipw,
               const float* __restrict__ opw, const float* __restrict__ w1,
               u16* __restrict__ Fb, u16* __restrict__ ipwb,
               u16* __restrict__ opwb, u16* __restrict__ w1b)
{
    size_t i4 = ((size_t)blockIdx.x * 256 + threadIdx.x) * 4;
    const float* src; u16* dst; size_t off;
    if      (i4 < 2359296) { src = F;   dst = Fb;   off = i4; }
    else if (i4 < 3145728) { src = ipw; dst = ipwb; off = i4 - 2359296; }
    else if (i4 < 3407872) { src = opw; dst = opwb; off = i4 - 3145728; }
    else                   { src = w1;  dst = w1b;  off = i4 - 3407872; }
    float4 v = *(const float4*)(src + off);
    uint2 o; o.x = pack2(v.x, v.y); o.y = pack2(v.z, v.w);
    *(uint2*)(dst + off) = o;
}

// ---------------------------------------------------------------------------
// bf16 MFMA GEMM, 64x128 tile, BK=64, DMA staging. For qkv: 864 blocks.
// QSCALE: cols<512 scaled by log2(e)/8 (attention prescale, exp2 downstream).
// ---------------------------------------------------------------------------
template<bool RESID, bool OUT_BF16, bool QSCALE>
__global__ __launch_bounds__(256)
void gemm_mfma64(const u16* __restrict__ A, const u16* __restrict__ Bw,
                 const float* __restrict__ bias, const float* __restrict__ res,
                 void* __restrict__ Cv, int Mr, int Nc, int Kd)
{
    __shared__ uint4 As4[512];
    __shared__ uint4 Bs4[1024];
    const int tid = threadIdx.x;
    const int lane = tid & 63, w = tid >> 6;
    const int wu = __builtin_amdgcn_readfirstlane(w);
    const int r16 = lane & 15, quad = lane >> 4;
    const int r0 = blockIdx.y << 6, c0 = blockIdx.x << 7;

    const u16* pA[2]; const u16* pB[4];
    #pragma unroll
    for (int rd = 0; rd < 2; ++rd) {
        const int c = (rd << 8) + tid;            // 0..511
        const int kb = c >> 8, g = (c >> 6) & 3, rr = (c >> 2) & 15, q = c & 3;
        pA[rd] = A + (size_t)(r0 + (g << 4) + rr) * Kd + (kb << 5) + (q << 3);
    }
    #pragma unroll
    for (int rd = 0; rd < 4; ++rd) {
        const int c = (rd << 8) + tid;            // 0..1023
        const int kb = c >> 9, g = (c >> 6) & 7, rr = (c >> 2) & 15, q = c & 3;
        pB[rd] = Bw + (size_t)(c0 + (g << 4) + rr) * Kd + (kb << 5) + (q << 3);
    }

    f32x4 acc[4][2];
    #pragma unroll
    for (int i = 0; i < 4; ++i)
        #pragma unroll
        for (int j = 0; j < 2; ++j) acc[i][j] = (f32x4){0.f, 0.f, 0.f, 0.f};

    for (int kk = 0; kk < Kd; kk += 64) {
        __syncthreads();
        #pragma unroll
        for (int rd = 0; rd < 2; ++rd)
            load_lds16(pA[rd] + kk, (void*)(As4 + (rd << 8) + (wu << 6)));
        #pragma unroll
        for (int rd = 0; rd < 4; ++rd)
            load_lds16(pB[rd] + kk, (void*)(Bs4 + (rd << 8) + (wu << 6)));
        __syncthreads();
        #pragma unroll
        for (int kb = 0; kb < 2; ++kb) {
            bf16x8 af[4], bfr[2];
            #pragma unroll
            for (int i = 0; i < 4; ++i)
                af[i] = *(const bf16x8*)&As4[((kb * 4 + i) << 6) + (r16 << 2) + quad];
            #pragma unroll
            for (int j = 0; j < 2; ++j)
                bfr[j] = *(const bf16x8*)&Bs4[((kb * 8 + (w << 1) + j) << 6) + (r16 << 2) + quad];
            #pragma unroll
            for (int i = 0; i < 4; ++i)
                #pragma unroll
                for (int j = 0; j < 2; ++j)
                    acc[i][j] = __builtin_amdgcn_mfma_f32_16x16x32_bf16(af[i], bfr[j], acc[i][j], 0, 0, 0);
        }
    }

    float bcol[2], scl[2];
    #pragma unroll
    for (int j = 0; j < 2; ++j) {
        const int col = c0 + (w << 5) + (j << 4) + r16;
        bcol[j] = bias[col];
        scl[j] = (QSCALE && col < 512) ? 0.180336880111120426f : 1.0f;  // log2(e)/8
    }
    #pragma unroll
    for (int i = 0; i < 4; ++i) {
        #pragma unroll
        for (int reg = 0; reg < 4; ++reg) {
            const int row = r0 + (i << 4) + (quad << 2) + reg;
            const size_t base = (size_t)row * Nc;
            #pragma unroll
            for (int j = 0; j < 2; ++j) {
                const int col = c0 + (w << 5) + (j << 4) + r16;
                float v = acc[i][j][reg] + bcol[j];
                if (RESID) v += res[base + col];
                if (QSCALE) v *= scl[j];
                if (OUT_BF16) ((u16*)Cv)[base + col] = f2bf(v);
                else          ((float*)Cv)[base + col] = v;
            }
        }
    }
}

// ---------------------------------------------------------------------------
// bf16 MFMA GEMM, 64x64 tile, BK=64: 576 blocks for the Nc=512 GEMMs.
// Waves 2x2, each 32x32 (2x2 frags, 16 acc VGPRs). DMA staging.
// ---------------------------------------------------------------------------
template<bool RESID, bool OUT_BF16>
__global__ __launch_bounds__(256)
void gemm_6464(const u16* __restrict__ A, const u16* __restrict__ Bw,
               const float* __restrict__ bias, const float* __restrict__ res,
               void* __restrict__ Cv, int Mr, int Nc, int Kd)
{
    __shared__ uint4 As4[512];
    __shared__ uint4 Bs4[512];
    const int tid = threadIdx.x;
    const int lane = tid & 63, w = tid >> 6;
    const int wu = __builtin_amdgcn_readfirstlane(w);
    const int r16 = lane & 15, quad = lane >> 4;
    const int wy = w >> 1, wx = w & 1;
    const int r0 = blockIdx.y << 6, c0 = blockIdx.x << 6;

    const u16* pA[2]; const u16* pB[2];
    #pragma unroll
    for (int rd = 0; rd < 2; ++rd) {
        const int c = (rd << 8) + tid;            // 0..511
        const int kb = c >> 8, g = (c >> 6) & 3, rr = (c >> 2) & 15, q = c & 3;
        const int row = (g << 4) + rr;
        const int koff = (kb << 5) + (q << 3);
        pA[rd] = A  + (size_t)(r0 + row) * Kd + koff;
        pB[rd] = Bw + (size_t)(c0 + row) * Kd + koff;
    }

    f32x4 acc[2][2];
    #pragma unroll
    for (int i = 0; i < 2; ++i)
        #pragma unroll
        for (int j = 0; j < 2; ++j) acc[i][j] = (f32x4){0.f, 0.f, 0.f, 0.f};

    for (int kk = 0; kk < Kd; kk += 64) {
        __syncthreads();
        #pragma unroll
        for (int rd = 0; rd < 2; ++rd) {
            load_lds16(pA[rd] + kk, (void*)(As4 + (rd << 8) + (wu << 6)));
            load_lds16(pB[rd] + kk, (void*)(Bs4 + (rd << 8) + (wu << 6)));
        }
        __syncthreads();
        #pragma unroll
        for (int kb = 0; kb < 2; ++kb) {
            bf16x8 af[2], bfr[2];
            #pragma unroll
            for (int i = 0; i < 2; ++i)
                af[i] = *(const bf16x8*)&As4[((kb * 4 + (wy << 1) + i) << 6) + (r16 << 2) + quad];
            #pragma unroll
            for (int j = 0; j < 2; ++j)
                bfr[j] = *(const bf16x8*)&Bs4[((kb * 4 + (wx << 1) + j) << 6) + (r16 << 2) + quad];
            #pragma unroll
            for (int i = 0; i < 2; ++i)
                #pragma unroll
                for (int j = 0; j < 2; ++j)
                    acc[i][j] = __builtin_amdgcn_mfma_f32_16x16x32_bf16(af[i], bfr[j], acc[i][j], 0, 0, 0);
        }
    }

    float bcol[2];
    #pragma unroll
    for (int j = 0; j < 2; ++j) bcol[j] = bias[c0 + (wx << 5) + (j << 4) + r16];
    #pragma unroll
    for (int i = 0; i < 2; ++i) {
        #pragma unroll
        for (int reg = 0; reg < 4; ++reg) {
            const int row = r0 + (wy << 5) + (i << 4) + (quad << 2) + reg;
            const size_t base = (size_t)row * Nc;
            #pragma unroll
            for (int j = 0; j < 2; ++j) {
                const int col = c0 + (wx << 5) + (j << 4) + r16;
                float v = acc[i][j][reg] + bcol[j];
                if (RESID) v += res[base + col];
                if (OUT_BF16) ((u16*)Cv)[base + col] = f2bf(v);
                else          ((float*)Cv)[base + col] = v;
            }
        }
    }
}

// ---------------------------------------------------------------------------
// bf16 MFMA flash attention, no-max softmax (q prescaled by log2e/8 -> exp2).
// K via DMA. V scatter paired as ds_write_b32 (each thread stages rows 2p,
// 2p+1); Vfs XOR-swizzled, Pfs digit-permuted (both <=4-way conflicts).
// ---------------------------------------------------------------------------
__global__ __launch_bounds__(256)
void attn_mfma(const u16* __restrict__ qkv, u16* __restrict__ obuf)
{
    __shared__ uint4 Qf[512];
    __shared__ uint4 Kf[512];
    __shared__ u16  Vfs[4096];
    __shared__ u16  Pfs[4096];
    const int tid = threadIdx.x;
    const int lane = tid & 63, w = tid >> 6;
    const int wu = __builtin_amdgcn_readfirstlane(w);
    const int r16 = lane & 15, quad = lane >> 4;
    const int b = blockIdx.y >> 3, h = blockIdx.y & 7;
    const int i0 = blockIdx.x << 6;
    const u16* qb = qkv + (size_t)b * NNB * 1536 + h * 64;

    #pragma unroll
    for (int s = 0; s < 2; ++s) {        // stage Q once
        const int linear = (s << 8) + tid;
        const int r = linear >> 3, q7 = linear & 7;
        uint4 v = *(const uint4*)(qb + (size_t)(i0 + r) * 1536 + (q7 << 3));
        Qf[(((q7 >> 2) * 4 + (r >> 4)) << 6) + ((r & 15) << 2) + (q7 & 3)] = v;
    }
    const u16* pK[2];
    #pragma unroll
    for (int rd = 0; rd < 2; ++rd) {
        const int c = (rd << 8) + tid;
        const int kb = c >> 8, g = (c >> 6) & 3, rr = (c >> 2) & 15, q = c & 3;
        pK[rd] = qb + 512 + (size_t)((g << 4) + rr) * 1536 + (kb << 5) + (q << 3);
    }
    const int vp = tid >> 3, vq7 = tid & 7;     // V pair id / d-slice
    const int vj = vp << 1;
    const int vjl2 = (vj & 7) >> 1, vjq = (vj >> 3) & 3, vjkb = vj >> 5;

    float l_i[4] = {0.f, 0.f, 0.f, 0.f};
    f32x4 accO[4];
    #pragma unroll
    for (int f = 0; f < 4; ++f) accO[f] = (f32x4){0.f, 0.f, 0.f, 0.f};

    for (int j0 = 0; j0 < NNB; j0 += 64) {
        const u16* vbase = qb + 1024 + (size_t)(j0 + vj) * 1536 + (vq7 << 3);
        uint4 vA = *(const uint4*)vbase;
        uint4 vB = *(const uint4*)(vbase + 1536);
        __syncthreads();                 // previous iter's readers done
        load_lds16(pK[0] + (size_t)j0 * 1536, (void*)(Kf + (wu << 6)));
        load_lds16(pK[1] + (size_t)j0 * 1536, (void*)(Kf + 256 + (wu << 6)));
        {
            const u16* ea = (const u16*)&vA;
            const u16* eb = (const u16*)&vB;
            unsigned* V32 = (unsigned*)Vfs;
            #pragma unroll
            for (int e = 0; e < 8; ++e) {
                const int d = (vq7 << 3) + e;
                const int g = d >> 4;
                const int ch = ((vjkb * 4 + g) << 6) + ((((d & 15) << 2) + vjq) ^ g);
                V32[(ch << 2) + vjl2] = (unsigned)ea[e] | ((unsigned)eb[e] << 16);
            }
        }
        __syncthreads();

        f32x4 accS[4];
        #pragma unroll
        for (int f = 0; f < 4; ++f) accS[f] = (f32x4){0.f, 0.f, 0.f, 0.f};
        #pragma unroll
        for (int kb = 0; kb < 2; ++kb) {
            bf16x8 aq = *(const bf16x8*)&Qf[((kb * 4 + w) << 6) + (r16 << 2) + quad];
            #pragma unroll
            for (int f = 0; f < 4; ++f) {
                bf16x8 bk = *(const bf16x8*)&Kf[((kb * 4 + f) << 6) + (r16 << 2) + quad];
                accS[f] = __builtin_amdgcn_mfma_f32_16x16x32_bf16(aq, bk, accS[f], 0, 0, 0);
            }
        }
        #pragma unroll
        for (int reg = 0; reg < 4; ++reg) {
            const float s0 = exp2f(accS[0][reg]);
            const float s1 = exp2f(accS[1][reg]);
            const float s2 = exp2f(accS[2][reg]);
            const float s3 = exp2f(accS[3][reg]);
            l_i[reg] += (s0 + s1) + (s2 + s3);
            const int m = (quad << 2) + reg;
            const int sm = ((m & 3) << 2) + (m >> 2);     // digit-permuted m
            const float pv[4] = {s0, s1, s2, s3};
            #pragma unroll
            for (int f = 0; f < 4; ++f) {
                const int k = (f << 4) + r16;
                const int ch = (((k >> 5) * 4 + w) << 6) + (((k >> 3) & 3) << 4) + sm;
                Pfs[(ch << 3) + (k & 7)] = f2bf(pv[f]);
            }
        }
        #pragma unroll
        for (int kb = 0; kb < 2; ++kb) {
            bf16x8 ap = *(const bf16x8*)&Pfs[((((kb * 4 + w) << 6) + (quad << 4) + ((r16 & 3) << 2) + (r16 >> 2)) << 3)];
            #pragma unroll
            for (int f = 0; f < 4; ++f) {
                bf16x8 bv = *(const bf16x8*)&Vfs[((((kb * 4 + f) << 6) + (((r16 << 2) + quad) ^ f)) << 3)];
                accO[f] = __builtin_amdgcn_mfma_f32_16x16x32_bf16(ap, bv, accO[f], 0, 0, 0);
            }
        }
    }
    #pragma unroll
    for (int reg = 0; reg < 4; ++reg) {
        float l = l_i[reg];
        l += __shfl_xor(l, 1); l += __shfl_xor(l, 2);
        l += __shfl_xor(l, 4); l += __shfl_xor(l, 8);
        const float inv = 1.0f / l;
        const size_t row = (size_t)(b * NNB + i0 + (w << 4) + (quad << 2) + reg);
        #pragma unroll
        for (int f = 0; f < 4; ++f)
            obuf[row * 512 + (h << 6) + (f << 4) + r16] = f2bf(accO[f][reg] * inv);
    }
}

// ---------------------------------------------------------------------------
// Fused: LN+GELU -> comp -> exact top-51 (exponent bisection with DPP-VALU
// counts; compacted distinct-key bisection w/ early exit) -> LDS-staged,
// fully-coalesced write of the dense sparse output (bit-exact values).
// ---------------------------------------------------------------------------
__global__ __launch_bounds__(256)
void outer_topk(const float* __restrict__ F, const float* __restrict__ hraw,
                const float* __restrict__ lng, const float* __restrict__ lnb,
                const float* __restrict__ w2, const float* __restrict__ b2,
                const float* __restrict__ T, float* __restrict__ out)
{
    const int bn = blockIdx.x;
    const int tid = threadIdx.x;
    const int lane = tid & 63, w = tid >> 6;
    __shared__ float Fr[512];
    __shared__ float Hr[512];
    __shared__ unsigned keyslots[4][4][64];
    __shared__ float redsm[8];
    // staging for coalesced output: vals[m][d_half], stride 258 dwords.
    // write side: lanes stride 1 -> conflict-free; read side: bank =
    // (258*m + dl) % 32 = (2m + dl) % 32 -> <=2-way (free, m136).
    __shared__ float vals[16 * 258];

    // --- load F row + raw h row; LN + exact GELU into Hr ---
    if (tid < 128)
        *(float4*)&Fr[tid << 2] = *(const float4*)(F + (size_t)bn * 512 + (tid << 2));
    const float* hp = hraw + (size_t)bn * 512;
    float x0 = hp[tid], x1 = hp[tid + 256];
    float sw = dpp_red_add_f(x0 + x1);
    float sqw = dpp_red_add_f(x0 * x0 + x1 * x1);
    if (lane == 0) { redsm[w] = sw; redsm[4 + w] = sqw; }
    __syncthreads();
    const float s  = redsm[0] + redsm[1] + redsm[2] + redsm[3];
    const float sq = redsm[4] + redsm[5] + redsm[6] + redsm[7];
    const float mean = s * (1.0f / 512.0f);
    const float var  = sq * (1.0f / 512.0f) - mean * mean;
    const float rstd = rsqrtf(var + 1e-5f);
    float y = (x0 - mean) * rstd * lng[tid] + lnb[tid];
    Hr[tid] = 0.5f * y * (1.0f + erff(y * 0.70710678118654752f));
    y = (x1 - mean) * rstd * lng[tid + 256] + lnb[tid + 256];
    Hr[tid + 256] = 0.5f * y * (1.0f + erff(y * 0.70710678118654752f));
    __syncthreads();

    // --- comp[m] = Hr . w2[m] + b2[m]; DPP reduce, uniform in all lanes ---
    const int m0 = w << 2;
    float cm[4];
    #pragma unroll
    for (int mi = 0; mi < 4; ++mi) {
        const float* w2p = w2 + (size_t)(m0 + mi) * 512;
        float p = 0.f;
        #pragma unroll
        for (int t = 0; t < 8; ++t) p += Hr[lane + (t << 6)] * w2p[lane + (t << 6)];
        cm[mi] = dpp_red_add_f(p) + b2[m0 + mi];
    }

    // --- abs bit patterns + sign mask (exact fp32 op order of reference) ---
    unsigned u[4][8]; unsigned smask[4];
    #pragma unroll
    for (int mi = 0; mi < 4; ++mi) {
        smask[mi] = 0u;
        const float* Tp = T + (size_t)(m0 + mi) * 512;
        #pragma unroll
        for (int t = 0; t < 8; ++t) {
            float pp = Fr[lane + (t << 6)] * Tp[lane + (t << 6)];
            float pc = pp * cm[mi];
            const unsigned bits = __float_as_uint(pc);
            u[mi][t] = bits & 0x7fffffffu;
            smask[mi] |= (bits >> 31) << t;
        }
    }

    // --- phase A: bisect exponent bits 30..23 (VALU counts + DPP reduce) ---
    unsigned pref[4] = {0u, 0u, 0u, 0u};
    int cntP[4] = {512, 512, 512, 512};
    int U[4] = {0, 0, 0, 0};
    for (int bit = 30; bit >= 23; --bit) {
        const unsigned msk = 1u << bit;
        unsigned cand[4]; int cl[4];
        #pragma unroll
        for (int mi = 0; mi < 4; ++mi) {
            cand[mi] = pref[mi] | msk;
            int cc = 0;
            #pragma unroll
            for (int t = 0; t < 8; ++t) cc += (u[mi][t] >= cand[mi]) ? 1 : 0;
            cl[mi] = cc;
        }
        int cnt[4];
        #pragma unroll
        for (int mi = 0; mi < 4; ++mi) cnt[mi] = dpp_red_add_i(cl[mi]);
        #pragma unroll
        for (int mi = 0; mi < 4; ++mi) {
            if (cnt[mi] >= KSEL) { pref[mi] = cand[mi]; cntP[mi] = cnt[mi]; }
            else U[mi] = cnt[mi];
        }
    }
    // rare: extend bisection until the tie bucket fits in 64 slots
    int blo[4];
    #pragma unroll
    for (int mi = 0; mi < 4; ++mi) {
        int b = 23;
        while ((cntP[mi] - U[mi]) > 64 && b > 0) {
            --b;
            const unsigned cand = pref[mi] | (1u << b);
            int cc = 0;
            #pragma unroll
            for (int t = 0; t < 8; ++t) cc += (u[mi][t] >= cand) ? 1 : 0;
            const int cnt = dpp_red_add_i(cc);
            if (cnt >= KSEL) { pref[mi] = cand; cntP[mi] = cnt; } else U[mi] = cnt;
        }
        blo[mi] = b;
    }
    int need[4]; bool done[4];
    #pragma unroll
    for (int mi = 0; mi < 4; ++mi) {
        need[mi] = KSEL - U[mi];
        done[mi] = (need[mi] == cntP[mi] - U[mi]);   // whole bucket selected
    }

    // --- compact tie bucket into distinct 32-bit keys, one slot per lane ---
    const unsigned long long lmask = (1ull << lane) - 1ull;
    unsigned kv[4] = {0u, 0u, 0u, 0u};
    #pragma unroll
    for (int mi = 0; mi < 4; ++mi) {
        if (done[mi]) continue;
        keyslots[w][mi][lane] = 0u;
        const int bl = blo[mi];
        const unsigned lowmask = (1u << bl) - 1u;
        int running = 0;
        #pragma unroll
        for (int t = 0; t < 8; ++t) {
            const bool tie = ((u[mi][t] ^ pref[mi]) >> bl) == 0u;
            const unsigned long long M = __ballot(tie);
            const int slot = running + __popcll(M & lmask);
            if (tie && slot < 64) {
                const unsigned key = ((u[mi][t] & lowmask) << 9) | (unsigned)(511 - ((t << 6) + lane));
                keyslots[w][mi][slot] = key;
            }
            running += __popcll(M);
        }
        kv[mi] = keyslots[w][mi][lane];
    }

    // --- phase B: bisect keys, 1 ballot/round, early exit on exact count ---
    unsigned prefk[4] = {0u, 0u, 0u, 0u};
    for (int bb = 31; bb >= 0; --bb) {
        if (done[0] & done[1] & done[2] & done[3]) break;
        #pragma unroll
        for (int mi = 0; mi < 4; ++mi) {
            if (done[mi]) continue;
            const unsigned candk = prefk[mi] | (1u << bb);
            const int c = __popcll(__ballot(kv[mi] >= candk));
            if (c >= need[mi]) {
                prefk[mi] = candk;
                if (c == need[mi]) done[mi] = true;
            }
        }
    }

    // --- write phase: stage bit-exact values in LDS (two 256-d passes),
    //     then emit fully-coalesced stores: each wave instruction writes
    //     1 KiB contiguous (lane-stride 16 B) instead of 16 B per 64 B line.
    float* ob = out + (size_t)bn * 8192;
    #pragma unroll
    for (int p = 0; p < 2; ++p) {
        if (p) __syncthreads();          // pass-0 LDS reads done before refill
        #pragma unroll
        for (int tt = 0; tt < 4; ++tt) {
            const int t = (p << 2) + tt;
            const int d = (t << 6) + lane;
            #pragma unroll
            for (int mi = 0; mi < 4; ++mi) {
                const unsigned uu = u[mi][t];
                const int bl = blo[mi];
                const bool tie = ((uu ^ pref[mi]) >> bl) == 0u;
                const unsigned key = ((uu & ((1u << bl) - 1u)) << 9) | (unsigned)(511 - d);
                const bool sel = (uu >= pref[mi] + (1u << bl)) || (tie && key >= prefk[mi]);
                const unsigned bits = uu | (((smask[mi] >> t) & 1u) << 31);
                vals[(m0 + mi) * 258 + (tt << 6) + lane] = sel ? __uint_as_float(bits) : 0.0f;
            }
        }
        __syncthreads();
        #pragma unroll
        for (int j = 0; j < 4; ++j) {
            // dword offset within this pass's 16 KiB region
            const int off = (w << 10) + (j << 8) + (lane << 2);
            const int dl = off >> 4;               // local d: 0..255
            const int ms = (lane & 3) << 2;        // m-chunk: 0,4,8,12
            float4 v;
            v.x = vals[(ms + 0) * 258 + dl];
            v.y = vals[(ms + 1) * 258 + dl];
            v.z = vals[(ms + 2) * 258 + dl];
            v.w = vals[(ms + 3) * 258 + dl];
            *(float4*)(ob + (p << 12) + off) = v;
        }
    }
}

// ---------------------------------------------------------------------------
extern "C" void kernel_launch(void* const* d_in, const int* in_sizes, int n_in,
                              void* d_out, int out_size, void* d_ws, size_t ws_size,
                              hipStream_t stream)
{
    const float* F    = (const float*)d_in[0];
    const float* ipw  = (const float*)d_in[1];
    const float* ipb  = (const float*)d_in[2];
    const float* opw  = (const float*)d_in[3];
    const float* opb  = (const float*)d_in[4];
    const float* w1   = (const float*)d_in[5];
    const float* b1   = (const float*)d_in[6];
    const float* lng  = (const float*)d_in[7];
    const float* lnb  = (const float*)d_in[8];
    const float* w2   = (const float*)d_in[9];
    const float* b2   = (const float*)d_in[10];
    const float* tmpl = (const float*)d_in[11];

    char* wsb = (char*)d_ws;
    u16*   qkvb  = (u16*)wsb;                     // 4608*1536 bf16
    u16*   obufb = (u16*)(wsb + 14155776);        // 4608*512 bf16
    u16*   fenhb = (u16*)(wsb + 18874368);        // 4608*512 bf16
    float* hbuf  = (float*)(wsb + 23592960);      // 4608*512 f32 (raw, pre-LN)
    u16*   Fbf   = (u16*)(wsb + 33030144);        // 4608*512 bf16
    u16*   ipwbf = (u16*)(wsb + 37748736);        // 1536*512 bf16
    u16*   opwbf = (u16*)(wsb + 39321600);        // 512*512 bf16
    u16*   w1bf  = (u16*)(wsb + 39845888);        // 512*512 bf16

    cast_bf16<<<3584, 256, 0, stream>>>(F, ipw, opw, w1, Fbf, ipwbf, opwbf, w1bf);
    // qkv = F @ ipw^T + ipb (q prescaled by log2e/8) -> bf16, 864 blocks
    gemm_mfma64<false, true, true><<<dim3(12, 72), 256, 0, stream>>>(Fbf, ipwbf, ipb, nullptr, qkvb, BNR, 1536, 512);
    // o = attention(qkv) -> bf16 [4608,512]
    attn_mfma<<<dim3(9, 64), 256, 0, stream>>>(qkvb, obufb);
    // F_enh = o @ opw^T + opb + F -> bf16, 576 blocks
    gemm_6464<true, true><<<dim3(8, 72), 256, 0, stream>>>(obufb, opwbf, opb, F, fenhb, BNR, 512, 512);
    // h_raw = F_enh @ w1^T + b1 -> fp32, 576 blocks
    gemm_6464<false, false><<<dim3(8, 72), 256, 0, stream>>>(fenhb, w1bf, b1, nullptr, hbuf, BNR, 512, 512);
    // LN+GELU + comp + exact top-51 + staged coalesced sparse write (fused)
    outer_topk<<<4608, 256, 0, stream>>>(F, hbuf, lng, lnb, w2, b2, tmpl, (float*)d_out);
}